// Round 11
// baseline (7902.104 us; speedup 1.0000x reference)
//
#include <hip/hip_runtime.h>
#include <math.h>

#define S_ 48
#define B_ 64
#define D_ 300
#define HE_ 300
#define HD_ 256
#define E_ 50
#define A_ 128
#define T_ 50
#define N_ (S_*B_)   // 3072

__device__ __forceinline__ float sigm(float x){ return 1.0f/(1.0f + expf(-x)); }

// ---------------------------------------------------------------------------
// Generic GEMM: C(M,N) = A(M,K) @ W(N,K)^T + bias(N)
// MODE 0: store C row-major (A2 unused)
// MODE 2: A-tile = A + A2 elementwise; v = tanh(acc+bias);
//         cols [0,256) -> C[m*256+n], [256,512) -> C2
// ---------------------------------------------------------------------------
template<int MODE>
__global__ __launch_bounds__(256)
void gemm_bias_kernel(const float* __restrict__ A, const float* __restrict__ A2,
                      const float* __restrict__ W,
                      const float* __restrict__ bias, float* __restrict__ C,
                      float* __restrict__ C2, int M, int N, int K)
{
  __shared__ float As[16][64];
  __shared__ float Ws[16][64];
  const int tid = threadIdx.x;
  const int bm = blockIdx.y * 64;
  const int bn = blockIdx.x * 64;
  const int tx = tid & 15, ty = tid >> 4;
  const int lr = tid >> 2;
  const int lk = (tid & 3) << 2;
  float acc[4][4] = {{0.f}};
  for (int kb = 0; kb < K; kb += 16) {
    {
      const int row = bm + lr;
      const int k = kb + lk;
      const float* ap = A + (size_t)row * K + k;
      float4 v = make_float4(0.f,0.f,0.f,0.f);
      if (k + 3 < K) v = *reinterpret_cast<const float4*>(ap);
      else {
        if (k   < K) v.x = ap[0];
        if (k+1 < K) v.y = ap[1];
        if (k+2 < K) v.z = ap[2];
        if (k+3 < K) v.w = ap[3];
      }
      if (MODE == 2) {
        const float* ap2 = A2 + (size_t)row * K + k;
        if (k + 3 < K) {
          float4 v2 = *reinterpret_cast<const float4*>(ap2);
          v.x += v2.x; v.y += v2.y; v.z += v2.z; v.w += v2.w;
        } else {
          if (k   < K) v.x += ap2[0];
          if (k+1 < K) v.y += ap2[1];
          if (k+2 < K) v.z += ap2[2];
          if (k+3 < K) v.w += ap2[3];
        }
      }
      As[lk][lr]=v.x; As[lk+1][lr]=v.y; As[lk+2][lr]=v.z; As[lk+3][lr]=v.w;
    }
    {
      const int col = bn + lr;
      const int k = kb + lk;
      float4 v = make_float4(0.f,0.f,0.f,0.f);
      if (col < N) {
        const float* wp = W + (size_t)col * K + k;
        if (k + 3 < K) v = *reinterpret_cast<const float4*>(wp);
        else {
          if (k   < K) v.x = wp[0];
          if (k+1 < K) v.y = wp[1];
          if (k+2 < K) v.z = wp[2];
          if (k+3 < K) v.w = wp[3];
        }
      }
      Ws[lk][lr]=v.x; Ws[lk+1][lr]=v.y; Ws[lk+2][lr]=v.z; Ws[lk+3][lr]=v.w;
    }
    __syncthreads();
    #pragma unroll
    for (int kk = 0; kk < 16; ++kk) {
      float4 a4 = *reinterpret_cast<const float4*>(&As[kk][ty<<2]);
      float4 w4 = *reinterpret_cast<const float4*>(&Ws[kk][tx<<2]);
      const float* a = reinterpret_cast<const float*>(&a4);
      const float* w = reinterpret_cast<const float*>(&w4);
      #pragma unroll
      for (int i = 0; i < 4; ++i)
        #pragma unroll
        for (int j = 0; j < 4; ++j)
          acc[i][j] = fmaf(a[i], w[j], acc[i][j]);
    }
    __syncthreads();
  }
  #pragma unroll
  for (int i = 0; i < 4; ++i) {
    const int m = bm + (ty<<2) + i;
    #pragma unroll
    for (int j = 0; j < 4; ++j) {
      const int n = bn + (tx<<2) + j;
      if (n < N) {
        float v = acc[i][j] + bias[n];
        if (MODE == 0) {
          C[(size_t)m*N + n] = v;
        } else {
          v = tanhf(v);
          if (n < HD_) C[(size_t)m*HD_ + n] = v;
          else         C2[(size_t)m*HD_ + (n-HD_)] = v;
        }
      }
    }
  }
}

// ---------------------------------------------------------------------------
// Padded transpose into strided destination:
// out[(row0+k)*dstride + coff + gc] = in[gc*NK + k]  (zero for k in [NK,NKP))
// ---------------------------------------------------------------------------
__global__ __launch_bounds__(256)
void ctranspose_kernel(const float* __restrict__ in, float* __restrict__ out,
                       int NC, int NK, int NKP, int dstride, int row0, int coff)
{
  int idx = blockIdx.x * 256 + threadIdx.x;
  if (idx < NC*NKP) {
    int gc = idx / NKP, k = idx % NKP;
    out[(size_t)(row0+k)*dstride + coff + gc] =
        (k < NK) ? in[(size_t)gc*NK + k] : 0.0f;
  }
}

// ---------------------------------------------------------------------------
// Pack weights into k-quad float4 layout: P[k4*NC + gc] = W[gc][4*k4 .. +3]
// (zero-padded past NK). W is (NC, NK) row-major.
// ---------------------------------------------------------------------------
__global__ __launch_bounds__(256)
void pack4_kernel(const float* __restrict__ W, float4* __restrict__ P,
                  int NC, int NK, int K4)
{
  int idx = blockIdx.x * 256 + threadIdx.x;
  if (idx >= NC * K4) return;
  int k4 = idx / NC, gc = idx % NC;
  int k = k4 << 2;
  const float* wp = W + (size_t)gc * NK + k;
  float4 v = make_float4(0.f,0.f,0.f,0.f);
  if (k   < NK) v.x = wp[0];
  if (k+1 < NK) v.y = wp[1];
  if (k+2 < NK) v.z = wp[2];
  if (k+3 < NK) v.w = wp[3];
  P[(size_t)k4 * NC + gc] = v;
}

// ---------------------------------------------------------------------------
// Persistent encoder layer: grid (16 row-groups, 2 dirs) = 32 blocks, 640 thr.
// (proven, verbatim)
// ---------------------------------------------------------------------------
template<int LAYER>
__global__ __launch_bounds__(640, 2)
void enc_layer_persistent(const float* __restrict__ gi_f, const float* __restrict__ gi_b,
                          const float* __restrict__ WhhT_f, const float* __restrict__ WhhT_b,
                          const float* __restrict__ bhh_f, const float* __restrict__ bhh_b,
                          float* __restrict__ out, float* __restrict__ outB)
{
  const int dir = blockIdx.y;
  const float* gi  = dir ? gi_b   : gi_f;
  const float* WT  = dir ? WhhT_b : WhhT_f;
  const float* bhh = dir ? bhh_b  : bhh_f;
  float* o = (LAYER == 1 && dir) ? outB : out;

  __shared__ float hA[4][304];
  __shared__ float hB[4][304];
  const int tid = threadIdx.x;
  const int half = tid / 320;
  const int j = tid - half*320;
  const int R0 = blockIdx.x * 4;
  const int r0 = half * 2;
  const bool act = (j < HE_);

  float b_r = 0.f, b_z = 0.f, b_n = 0.f;
  if (act) { b_r = bhh[j]; b_z = bhh[HE_+j]; b_n = bhh[2*HE_+j]; }
  __syncthreads();

  for (int t = 0; t < S_; ++t) {
    const int tt = dir ? (S_-1 - t) : t;
    float (*hin)[304]  = (t & 1) ? hB : hA;
    float (*hout)[304] = (t & 1) ? hA : hB;
    float ar[2]={0,0}, az[2]={0,0}, an[2]={0,0};
    if (act && t > 0) {
      for (int k = 0; k < HE_; k += 4) {
        float wr[4], wz[4], wn[4];
        #pragma unroll
        for (int u = 0; u < 4; ++u) {
          const float* wk = WT + (size_t)(k+u)*(3*HE_);
          wr[u] = wk[j]; wz[u] = wk[HE_+j]; wn[u] = wk[2*HE_+j];
        }
        #pragma unroll
        for (int r = 0; r < 2; ++r) {
          float4 h4 = *reinterpret_cast<const float4*>(&hin[r0+r][k]);
          ar[r]=fmaf(h4.x,wr[0],ar[r]); ar[r]=fmaf(h4.y,wr[1],ar[r]);
          ar[r]=fmaf(h4.z,wr[2],ar[r]); ar[r]=fmaf(h4.w,wr[3],ar[r]);
          az[r]=fmaf(h4.x,wz[0],az[r]); az[r]=fmaf(h4.y,wz[1],az[r]);
          az[r]=fmaf(h4.z,wz[2],az[r]); az[r]=fmaf(h4.w,wz[3],az[r]);
          an[r]=fmaf(h4.x,wn[0],an[r]); an[r]=fmaf(h4.y,wn[1],an[r]);
          an[r]=fmaf(h4.z,wn[2],an[r]); an[r]=fmaf(h4.w,wn[3],an[r]);
        }
      }
    }
    if (act) {
      #pragma unroll
      for (int r = 0; r < 2; ++r) {
        const int row = R0 + r0 + r;
        const size_t gb = (size_t)(tt*B_ + row) * (3*HE_);
        float gr = gi[gb + j];
        float gz = gi[gb + HE_ + j];
        float gn = gi[gb + 2*HE_ + j];
        float rg = sigm(gr + ar[r] + b_r);
        float zg = sigm(gz + az[r] + b_z);
        float ng = tanhf(gn + rg*(an[r] + b_n));
        float ho = (t > 0) ? hin[r0+r][j] : 0.0f;
        float hn = (1.0f - zg)*ng + zg*ho;
        hout[r0+r][j] = hn;
        if (LAYER == 0) o[(size_t)(tt*B_ + row)*(2*HE_) + dir*HE_ + j] = hn;
        else            o[(size_t)(tt*B_ + row)*HE_ + j] = hn;
      }
    }
    __syncthreads();
  }
}

// ---------------------------------------------------------------------------
// Persistent decoder, gate-column ownership. 256 blocks x 768 threads
// (12 waves/CU). Thread g owns gate-col g (gt = g>>8: 0=r,1=z,2=n; c = g&255)
// and accumulates its gate over all 12 rows -> each weight float4 is loaded
// by EXACTLY ONE thread per block. r/z threads pass raw sums via LDS; n
// threads hold ani/anh in regs and do the GRU combine. FMA chains per output
// are operand-identical to round 9 (absmax must stay 0.03125).
// ---------------------------------------------------------------------------
__global__ __launch_bounds__(768)
void dec_persistent(const float4* __restrict__ Wih0P,  // [13][768]
                    const float4* __restrict__ Whh0P,  // [64][768]
                    const float4* __restrict__ Wih1P,  // [64][768]
                    const float4* __restrict__ Whh1P,  // [64][768]
                    const float* __restrict__ WoutT,   // [256][128]
                    const float* __restrict__ bih0, const float* __restrict__ bhh0,
                    const float* __restrict__ bih1, const float* __restrict__ bhh1,
                    const float* __restrict__ bout,
                    const float* __restrict__ emb,
                    const float* __restrict__ h0init, const float* __restrict__ h1init,
                    float* __restrict__ Y)
{
  __shared__ __align__(16) float h0s[12][256];
  __shared__ __align__(16) float h1s[12][256];
  __shared__ __align__(16) float es[12][56];
  __shared__ float grs[12][256];
  __shared__ float gzs[12][256];
  const int tid = threadIdx.x;     // 0..767
  const int R0 = blockIdx.x * 12;
  const int g  = tid;              // gate-col
  const int c  = tid & 255;
  const int gt = tid >> 8;         // 0=r, 1=z, 2=n
  const int lane = tid & 63;
  const int wave = tid >> 6;       // 0..11

  for (int i = tid; i < 12*64; i += 768) {
    int r = i >> 6, k = (i & 63) << 2;
    *reinterpret_cast<float4*>(&h0s[r][k]) =
        *reinterpret_cast<const float4*>(&h0init[(size_t)(R0+r)*HD_ + k]);
    *reinterpret_cast<float4*>(&h1s[r][k]) =
        *reinterpret_cast<const float4*>(&h1init[(size_t)(R0+r)*HD_ + k]);
  }
  for (int i = tid; i < 12*56; i += 768) {
    int r = i / 56, k = i - r*56;
    es[r][k] = (k < E_) ? emb[E_ + k] : 0.0f;   // emb[SOS=1], zero pad
  }
  const float b0r = bih0[c] + bhh0[c];
  const float b0z = bih0[HD_+c] + bhh0[HD_+c];
  const float b0ni = bih0[2*HD_+c];
  const float b0nh = bhh0[2*HD_+c];
  const float b1r = bih1[c] + bhh1[c];
  const float b1z = bih1[HD_+c] + bhh1[HD_+c];
  const float b1ni = bih1[2*HD_+c];
  const float b1nh = bhh1[2*HD_+c];
  const float bo0 = bout[lane];
  const float bo1 = bout[64 + lane];
  __syncthreads();

  for (int s = 0; s < T_-1; ++s) {
    // =================== cell 0: gate k-loops (per gate type) ==============
    if (gt < 2) {
      float acc[12];
      #pragma unroll
      for (int r = 0; r < 12; ++r) acc[r] = 0.f;
      for (int kq = 0; kq < 64; ++kq) {
        const int k = kq << 2;
        float4 w = Whh0P[kq*768 + g];
        #pragma unroll
        for (int r = 0; r < 12; ++r) {
          float4 x = *reinterpret_cast<const float4*>(&h0s[r][k]);
          acc[r]=fmaf(x.x,w.x,acc[r]); acc[r]=fmaf(x.y,w.y,acc[r]);
          acc[r]=fmaf(x.z,w.z,acc[r]); acc[r]=fmaf(x.w,w.w,acc[r]);
        }
        if (kq < 13) {
          float4 v = Wih0P[kq*768 + g];
          #pragma unroll
          for (int r = 0; r < 12; ++r) {
            float4 e = *reinterpret_cast<const float4*>(&es[r][k]);
            acc[r]=fmaf(e.x,v.x,acc[r]); acc[r]=fmaf(e.y,v.y,acc[r]);
            acc[r]=fmaf(e.z,v.z,acc[r]); acc[r]=fmaf(e.w,v.w,acc[r]);
          }
        }
      }
      if (gt == 0) {
        #pragma unroll
        for (int r = 0; r < 12; ++r) grs[r][c] = acc[r];
      } else {
        #pragma unroll
        for (int r = 0; r < 12; ++r) gzs[r][c] = acc[r];
      }
      __syncthreads();
      __syncthreads();
    } else {
      float ani[12], anh[12];
      #pragma unroll
      for (int r = 0; r < 12; ++r) { ani[r] = 0.f; anh[r] = 0.f; }
      for (int kq = 0; kq < 64; ++kq) {
        const int k = kq << 2;
        float4 w = Whh0P[kq*768 + g];
        #pragma unroll
        for (int r = 0; r < 12; ++r) {
          float4 x = *reinterpret_cast<const float4*>(&h0s[r][k]);
          anh[r]=fmaf(x.x,w.x,anh[r]); anh[r]=fmaf(x.y,w.y,anh[r]);
          anh[r]=fmaf(x.z,w.z,anh[r]); anh[r]=fmaf(x.w,w.w,anh[r]);
        }
        if (kq < 13) {
          float4 v = Wih0P[kq*768 + g];
          #pragma unroll
          for (int r = 0; r < 12; ++r) {
            float4 e = *reinterpret_cast<const float4*>(&es[r][k]);
            ani[r]=fmaf(e.x,v.x,ani[r]); ani[r]=fmaf(e.y,v.y,ani[r]);
            ani[r]=fmaf(e.z,v.z,ani[r]); ani[r]=fmaf(e.w,v.w,ani[r]);
          }
        }
      }
      __syncthreads();    // grs/gzs ready
      #pragma unroll
      for (int r = 0; r < 12; ++r) {
        float rg = sigm(grs[r][c] + b0r);
        float zg = sigm(gzs[r][c] + b0z);
        float ng = tanhf(ani[r] + b0ni + rg*(anh[r] + b0nh));
        float hold = h0s[r][c];
        h0s[r][c] = (1.0f - zg)*ng + zg*hold;
      }
      __syncthreads();    // h0s stable
    }
    // =================== cell 1: gate k-loops ==============================
    if (gt < 2) {
      float acc[12];
      #pragma unroll
      for (int r = 0; r < 12; ++r) acc[r] = 0.f;
      for (int kq = 0; kq < 64; ++kq) {
        const int k = kq << 2;
        float4 v = Wih1P[kq*768 + g];
        float4 w = Whh1P[kq*768 + g];
        #pragma unroll
        for (int r = 0; r < 12; ++r) {
          float4 x = *reinterpret_cast<const float4*>(&h0s[r][k]);
          acc[r]=fmaf(x.x,v.x,acc[r]); acc[r]=fmaf(x.y,v.y,acc[r]);
          acc[r]=fmaf(x.z,v.z,acc[r]); acc[r]=fmaf(x.w,v.w,acc[r]);
          float4 y = *reinterpret_cast<const float4*>(&h1s[r][k]);
          acc[r]=fmaf(y.x,w.x,acc[r]); acc[r]=fmaf(y.y,w.y,acc[r]);
          acc[r]=fmaf(y.z,w.z,acc[r]); acc[r]=fmaf(y.w,w.w,acc[r]);
        }
      }
      if (gt == 0) {
        #pragma unroll
        for (int r = 0; r < 12; ++r) grs[r][c] = acc[r];
      } else {
        #pragma unroll
        for (int r = 0; r < 12; ++r) gzs[r][c] = acc[r];
      }
      __syncthreads();
      __syncthreads();
    } else {
      float ani[12], anh[12];
      #pragma unroll
      for (int r = 0; r < 12; ++r) { ani[r] = 0.f; anh[r] = 0.f; }
      for (int kq = 0; kq < 64; ++kq) {
        const int k = kq << 2;
        float4 v = Wih1P[kq*768 + g];
        float4 w = Whh1P[kq*768 + g];
        #pragma unroll
        for (int r = 0; r < 12; ++r) {
          float4 x = *reinterpret_cast<const float4*>(&h0s[r][k]);
          ani[r]=fmaf(x.x,v.x,ani[r]); ani[r]=fmaf(x.y,v.y,ani[r]);
          ani[r]=fmaf(x.z,v.z,ani[r]); ani[r]=fmaf(x.w,v.w,ani[r]);
          float4 y = *reinterpret_cast<const float4*>(&h1s[r][k]);
          anh[r]=fmaf(y.x,w.x,anh[r]); anh[r]=fmaf(y.y,w.y,anh[r]);
          anh[r]=fmaf(y.z,w.z,anh[r]); anh[r]=fmaf(y.w,w.w,anh[r]);
        }
      }
      __syncthreads();
      #pragma unroll
      for (int r = 0; r < 12; ++r) {
        float rg = sigm(grs[r][c] + b1r);
        float zg = sigm(gzs[r][c] + b1z);
        float ng = tanhf(ani[r] + b1ni + rg*(anh[r] + b1nh));
        float hold = h1s[r][c];
        h1s[r][c] = (1.0f - zg)*ng + zg*hold;
      }
      __syncthreads();
    }
    // ===== logits + log_softmax + argmax + emb feedback (1 row per wave) ===
    {
      const int rr = wave;   // 0..11
      float a0 = 0.f, a1 = 0.f;
      for (int k = 0; k < HD_; k += 2) {
        float w00 = WoutT[(size_t)k*A_ + lane];
        float w01 = WoutT[(size_t)k*A_ + 64 + lane];
        float w10 = WoutT[(size_t)(k+1)*A_ + lane];
        float w11 = WoutT[(size_t)(k+1)*A_ + 64 + lane];
        float2 hv = *reinterpret_cast<const float2*>(&h1s[rr][k]);
        a0 = fmaf(hv.x, w00, a0); a0 = fmaf(hv.y, w10, a0);
        a1 = fmaf(hv.x, w01, a1); a1 = fmaf(hv.y, w11, a1);
      }
      float v0 = a0 + bo0;
      float v1 = a1 + bo1;
      float mx = fmaxf(v0, v1);
      #pragma unroll
      for (int off = 32; off >= 1; off >>= 1) mx = fmaxf(mx, __shfl_xor(mx, off));
      float sum = expf(v0 - mx) + expf(v1 - mx);
      #pragma unroll
      for (int off = 32; off >= 1; off >>= 1) sum += __shfl_xor(sum, off);
      float lz = mx + logf(sum);
      float* Yr = Y + ((size_t)s*N_ + R0 + rr)*A_;
      Yr[lane]      = v0 - lz;
      Yr[64 + lane] = v1 - lz;
      float bv; int bi;
      if (v0 >= v1) { bv = v0; bi = lane; } else { bv = v1; bi = 64 + lane; }
      #pragma unroll
      for (int off = 32; off >= 1; off >>= 1) {
        float ov = __shfl_xor(bv, off);
        int   oi = __shfl_xor(bi, off);
        if (ov > bv || (ov == bv && oi < bi)) { bv = ov; bi = oi; }
      }
      if (lane < E_) es[rr][lane] = emb[(size_t)bi*E_ + lane];
    }
    __syncthreads();
  }
}

// ---------------------------------------------------------------------------
extern "C" void kernel_launch(void* const* d_in, const int* in_sizes, int n_in,
                              void* d_out, int out_size, void* d_ws, size_t ws_size,
                              hipStream_t stream)
{
  (void)in_sizes; (void)n_in; (void)out_size; (void)ws_size;
  const float* wv      = (const float*)d_in[0];
  const float* e0f_Wih = (const float*)d_in[1];
  const float* e0f_Whh = (const float*)d_in[2];
  const float* e0f_bih = (const float*)d_in[3];
  const float* e0f_bhh = (const float*)d_in[4];
  const float* e0b_Wih = (const float*)d_in[5];
  const float* e0b_Whh = (const float*)d_in[6];
  const float* e0b_bih = (const float*)d_in[7];
  const float* e0b_bhh = (const float*)d_in[8];
  const float* e1f_Wih = (const float*)d_in[9];
  const float* e1f_Whh = (const float*)d_in[10];
  const float* e1f_bih = (const float*)d_in[11];
  const float* e1f_bhh = (const float*)d_in[12];
  const float* e1b_Wih = (const float*)d_in[13];
  const float* e1b_Whh = (const float*)d_in[14];
  const float* e1b_bih = (const float*)d_in[15];
  const float* e1b_bhh = (const float*)d_in[16];
  const float* d0_Wih  = (const float*)d_in[17];
  const float* d0_Whh  = (const float*)d_in[18];
  const float* d0_bih  = (const float*)d_in[19];
  const float* d0_bhh  = (const float*)d_in[20];
  const float* d1_Wih  = (const float*)d_in[21];
  const float* d1_Whh  = (const float*)d_in[22];
  const float* d1_bih  = (const float*)d_in[23];
  const float* d1_bhh  = (const float*)d_in[24];
  const float* emb     = (const float*)d_in[25];
  const float* Wout    = (const float*)d_in[26];
  const float* bout    = (const float*)d_in[27];
  const float* Wh0     = (const float*)d_in[28];
  const float* bh0     = (const float*)d_in[29];

  float* ws = (float*)d_ws;
  float* giA  = ws;                                   // 2,764,800
  float* giB  = giA + (size_t)N_*3*HE_;               // 2,764,800
  float* x0   = giB + (size_t)N_*3*HE_;               // 1,843,200
  float* eWhT = x0  + (size_t)N_*2*HE_;               // 1,080,000 (4 x 270,000)
  float* eT0f = eWhT;
  float* eT0b = eT0f + (size_t)3*HE_*HE_;
  float* eT1f = eT0b + (size_t)3*HE_*HE_;
  float* eT1b = eT1f + (size_t)3*HE_*HE_;
  // aliases (stream-ordered reuse):
  float* encF = x0;                                   // after gi1 gemms, x0 dead
  float* encB = x0 + (size_t)N_*HE_;
  float* h0A  = giA;                                  // after L1, gi dead
  float* h1A  = giA + (size_t)N_*HD_;
  // packed decoder weights reuse eWhT (dead after enc L1):
  // (13+64+64+64)*768*4 + 256*128 = 662,528 <= 1,080,000
  float4* Wih0P = (float4*)eWhT;                      // 13 x 768
  float4* Whh0P = Wih0P + (size_t)13*768;             // 64 x 768
  float4* Wih1P = Whh0P + (size_t)64*768;
  float4* Whh1P = Wih1P + (size_t)64*768;
  float*  WoutT = (float*)(Whh1P + (size_t)64*768);   // 256 x 128
  float* Y = (float*)d_out;

  const dim3 blk(256);

  // ---- encoder weight transposes (into eWhT) ----
  ctranspose_kernel<<<dim3(1055), blk, 0, stream>>>(e0f_Whh, eT0f, 3*HE_, HE_, HE_, 3*HE_, 0, 0);
  ctranspose_kernel<<<dim3(1055), blk, 0, stream>>>(e0b_Whh, eT0b, 3*HE_, HE_, HE_, 3*HE_, 0, 0);
  ctranspose_kernel<<<dim3(1055), blk, 0, stream>>>(e1f_Whh, eT1f, 3*HE_, HE_, HE_, 3*HE_, 0, 0);
  ctranspose_kernel<<<dim3(1055), blk, 0, stream>>>(e1b_Whh, eT1b, 3*HE_, HE_, HE_, 3*HE_, 0, 0);
  // ---- encoder layer 0 ----
  gemm_bias_kernel<0><<<dim3(15,48), blk, 0, stream>>>(wv, nullptr, e0f_Wih, e0f_bih, giA, nullptr, N_, 3*HE_, D_);
  gemm_bias_kernel<0><<<dim3(15,48), blk, 0, stream>>>(wv, nullptr, e0b_Wih, e0b_bih, giB, nullptr, N_, 3*HE_, D_);
  enc_layer_persistent<0><<<dim3(16,2), dim3(640), 0, stream>>>(giA, giB, eT0f, eT0b, e0f_bhh, e0b_bhh, x0, nullptr);
  // ---- encoder layer 1 ----
  gemm_bias_kernel<0><<<dim3(15,48), blk, 0, stream>>>(x0, nullptr, e1f_Wih, e1f_bih, giA, nullptr, N_, 3*HE_, 2*HE_);
  gemm_bias_kernel<0><<<dim3(15,48), blk, 0, stream>>>(x0, nullptr, e1b_Wih, e1b_bih, giB, nullptr, N_, 3*HE_, 2*HE_);
  enc_layer_persistent<1><<<dim3(16,2), dim3(640), 0, stream>>>(giA, giB, eT1f, eT1b, e1f_bhh, e1b_bhh, encF, encB);
  // ---- packed decoder weights (eWhT now dead) ----
  pack4_kernel<<<dim3(39),  blk, 0, stream>>>(d0_Wih, Wih0P, 3*HD_, E_,  13);
  pack4_kernel<<<dim3(192), blk, 0, stream>>>(d0_Whh, Whh0P, 3*HD_, HD_, 64);
  pack4_kernel<<<dim3(192), blk, 0, stream>>>(d1_Wih, Wih1P, 3*HD_, HD_, 64);
  pack4_kernel<<<dim3(192), blk, 0, stream>>>(d1_Whh, Whh1P, 3*HD_, HD_, 64);
  ctranspose_kernel<<<dim3(128), blk, 0, stream>>>(Wout, WoutT, A_, HD_, HD_, 128, 0, 0);
  // ---- decoder init: h = tanh((encF+encB)@Wh0^T + bh0) -> h0A, h1A ----
  gemm_bias_kernel<2><<<dim3(8,48), blk, 0, stream>>>(encF, encB, Wh0, bh0, h0A, h1A, N_, 2*HD_, HE_);
  // ---- persistent decoder (gate-column ownership) ----
  dec_persistent<<<dim3(N_/12), dim3(768), 0, stream>>>(
      Wih0P, Whh0P, Wih1P, Whh1P, WoutT,
      d0_bih, d0_bhh, d1_bih, d1_bhh, bout,
      emb, h0A, h1A, Y);
}